// Round 1
// baseline (168.408 us; speedup 1.0000x reference)
//
#include <hip/hip_runtime.h>
#include <hip/hip_bf16.h>

// NT-Xent loss, BS=4096, D=256, TAU=0.5.
// Pipeline: knorm (normalize fp32 -> bf16), kgemm (Gram matrix via MFMA,
// fused exp + row-sum), kfinal (pair/diag dots in fp32, log, mean).

#define N_ROWS 8192
#define BSZ    4096
#define DIM    256
#define INV_TAU 2.0f
#define EPS_REF 1e-8f
#define COS_EPS 1e-8f

typedef __attribute__((ext_vector_type(8))) __bf16 bf16x8;
typedef __attribute__((ext_vector_type(4))) float  f32x4;

__device__ __forceinline__ float bfbits2f(unsigned short u) {
    return __uint_as_float(((unsigned)u) << 16);
}

// ---------------- Kernel 1: row-normalize, emit bf16 zn[8192][256] ----------
__global__ __launch_bounds__(256) void knorm(const float* __restrict__ zi,
                                             const float* __restrict__ zj,
                                             __hip_bfloat16* __restrict__ zn) {
    const int row  = blockIdx.x * 4 + (threadIdx.x >> 6);
    const int lane = threadIdx.x & 63;
    const float* src = (row < BSZ) ? (zi + (size_t)row * DIM)
                                   : (zj + (size_t)(row - BSZ) * DIM);
    float4 v = ((const float4*)src)[lane];              // 4 elems/lane * 64 = 256
    float ss = v.x*v.x + v.y*v.y + v.z*v.z + v.w*v.w;
    #pragma unroll
    for (int off = 32; off >= 1; off >>= 1) ss += __shfl_xor(ss, off);
    const float inv = 1.0f / fmaxf(sqrtf(ss), COS_EPS);
    union { ushort4 u; __hip_bfloat16 h[4]; } o;
    o.h[0] = __float2bfloat16(v.x * inv);
    o.h[1] = __float2bfloat16(v.y * inv);
    o.h[2] = __float2bfloat16(v.z * inv);
    o.h[3] = __float2bfloat16(v.w * inv);
    ((ushort4*)zn)[(size_t)row * (DIM/4) + lane] = o.u;
}

// ---------------- Kernel 2: C = exp(zn.zn^T / tau), accumulate row sums -----
// Grid 64x64 blocks, each 128x128 output tile, K=256 in 4 chunks of 64.
// LDS layout: [row][k] bf16, row stride 128B, 16B blocks XOR-swizzled by
// (row&7) so fragment ds_read_b128 is <=2-way bank conflicted (free).
// global_load_lds width 16: lane i writes wave_base + 16*i; we pick each
// lane's GLOBAL address to realize the swizzle.
__global__ __launch_bounds__(256) void kgemm(const __hip_bfloat16* __restrict__ zn,
                                             float* __restrict__ rowsum) {
    __shared__ __align__(16) __hip_bfloat16 As[128 * 64];
    __shared__ __align__(16) __hip_bfloat16 Bs[128 * 64];
    const int bi = blockIdx.y;
    const int bj = blockIdx.x;
    const int w  = threadIdx.x >> 6;   // wave 0..3: rows w*32..w*32+31, all 128 cols
    const int l  = threadIdx.x & 63;

    f32x4 acc[2][8];
    #pragma unroll
    for (int mt = 0; mt < 2; ++mt)
        #pragma unroll
        for (int nt = 0; nt < 8; ++nt)
            acc[mt][nt] = (f32x4){0.f, 0.f, 0.f, 0.f};

    // Staging geometry (4 issues of 16B/lane cover one 16KB tile).
    int gA[4], gB[4], ldsOff[4];
    #pragma unroll
    for (int it = 0; it < 4; ++it) {
        const int off = it * 4096 + w * 1024 + l * 16;  // byte offset in tile
        const int row = off >> 7;                       // 0..127
        const int bst = (off >> 4) & 7;                 // stored 16B-block
        const int bg  = bst ^ (row & 7);                // global 16B-block (swizzle)
        gA[it] = (bi * 128 + row) * 512 + bg * 16;      // global byte offsets
        gB[it] = (bj * 128 + row) * 512 + bg * 16;
        ldsOff[it] = it * 4096 + w * 1024;              // wave-uniform LDS base
    }
    const char* gbase = (const char*)zn;

    #pragma unroll 1
    for (int kc = 0; kc < 4; ++kc) {
        __syncthreads();
        #pragma unroll
        for (int it = 0; it < 4; ++it) {
            __builtin_amdgcn_global_load_lds(
                (const __attribute__((address_space(1))) void*)(gbase + gA[it] + kc * 128),
                (__attribute__((address_space(3))) void*)((char*)As + ldsOff[it]),
                16, 0, 0);
            __builtin_amdgcn_global_load_lds(
                (const __attribute__((address_space(1))) void*)(gbase + gB[it] + kc * 128),
                (__attribute__((address_space(3))) void*)((char*)Bs + ldsOff[it]),
                16, 0, 0);
        }
        __syncthreads();
        #pragma unroll
        for (int ks = 0; ks < 2; ++ks) {   // two K=32 steps per 64-chunk
            bf16x8 af[2], bfr[8];
            #pragma unroll
            for (int mt = 0; mt < 2; ++mt) {
                const int r = w * 32 + mt * 16 + (l & 15);
                const int b = (ks * 4 + (l >> 4)) ^ (r & 7);
                af[mt] = *(const bf16x8*)((const char*)As + r * 128 + b * 16);
            }
            #pragma unroll
            for (int nt = 0; nt < 8; ++nt) {
                const int r = nt * 16 + (l & 15);
                const int b = (ks * 4 + (l >> 4)) ^ (r & 7);
                bfr[nt] = *(const bf16x8*)((const char*)Bs + r * 128 + b * 16);
            }
            #pragma unroll
            for (int mt = 0; mt < 2; ++mt)
                #pragma unroll
                for (int nt = 0; nt < 8; ++nt)
                    acc[mt][nt] = __builtin_amdgcn_mfma_f32_16x16x32_bf16(
                        af[mt], bfr[nt], acc[mt][nt], 0, 0, 0);
        }
    }

    // Epilogue: e = exp(sim/tau); per-row sums.
    // C/D layout (16x16x32): col = lane&15, row = (lane>>4)*4 + reg.
    float rs[2][4] = {{0.f,0.f,0.f,0.f},{0.f,0.f,0.f,0.f}};
    #pragma unroll
    for (int mt = 0; mt < 2; ++mt)
        #pragma unroll
        for (int nt = 0; nt < 8; ++nt)
            #pragma unroll
            for (int r = 0; r < 4; ++r)
                rs[mt][r] += __expf(acc[mt][nt][r] * INV_TAU);
    // reduce across the 16 lanes sharing a quad (cols 0..15 of each 16-tile)
    #pragma unroll
    for (int off = 1; off <= 8; off <<= 1)
        #pragma unroll
        for (int mt = 0; mt < 2; ++mt)
            #pragma unroll
            for (int r = 0; r < 4; ++r)
                rs[mt][r] += __shfl_xor(rs[mt][r], off);
    if ((l & 15) == 0) {
        const int q = l >> 4;
        #pragma unroll
        for (int mt = 0; mt < 2; ++mt)
            #pragma unroll
            for (int r = 0; r < 4; ++r)
                atomicAdd(&rowsum[bi * 128 + w * 32 + mt * 16 + q * 4 + r], rs[mt][r]);
    }
}

// ---------------- Kernel 3: finalize loss -----------------------------------
// loss_i = log(rowsum_i - e_ii + EPS) - dot(zn_i, zn_pair)/tau ; out = mean.
__global__ __launch_bounds__(256) void kfinal(const __hip_bfloat16* __restrict__ zn,
                                              const float* __restrict__ rowsum,
                                              float* __restrict__ out) {
    const int row  = blockIdx.x * 4 + (threadIdx.x >> 6);
    const int l    = threadIdx.x & 63;
    const int pr   = (row < BSZ) ? row + BSZ : row - BSZ;
    ushort4 a = ((const ushort4*)zn)[(size_t)row * 64 + l];
    ushort4 b = ((const ushort4*)zn)[(size_t)pr  * 64 + l];
    const float ax = bfbits2f(a.x), ay = bfbits2f(a.y), az = bfbits2f(a.z), aw = bfbits2f(a.w);
    const float bx = bfbits2f(b.x), by = bfbits2f(b.y), bz = bfbits2f(b.z), bw = bfbits2f(b.w);
    float pd = ax*bx + ay*by + az*bz + aw*bw;   // pair dot
    float sd = ax*ax + ay*ay + az*az + aw*aw;   // self dot (diagonal)
    #pragma unroll
    for (int off = 32; off >= 1; off >>= 1) {
        pd += __shfl_xor(pd, off);
        sd += __shfl_xor(sd, off);
    }
    __shared__ float part[4];
    if (l == 0) {
        const float neg = rowsum[row] - __expf(sd * INV_TAU);
        part[threadIdx.x >> 6] = logf(neg + EPS_REF) - pd * INV_TAU;
    }
    __syncthreads();
    if (threadIdx.x == 0)
        atomicAdd(out, (part[0] + part[1] + part[2] + part[3]) * (1.0f / (float)N_ROWS));
}

extern "C" void kernel_launch(void* const* d_in, const int* in_sizes, int n_in,
                              void* d_out, int out_size, void* d_ws, size_t ws_size,
                              hipStream_t stream) {
    const float* zi = (const float*)d_in[0];
    const float* zj = (const float*)d_in[1];
    float* out = (float*)d_out;

    __hip_bfloat16* zn = (__hip_bfloat16*)d_ws;                         // 4 MB
    float* rowsum = (float*)((char*)d_ws + (size_t)N_ROWS * DIM * 2);   // 32 KB

    hipMemsetAsync(rowsum, 0, N_ROWS * sizeof(float), stream);
    hipMemsetAsync(out, 0, sizeof(float), stream);

    knorm <<<N_ROWS / 4, 256, 0, stream>>>(zi, zj, zn);
    kgemm <<<dim3(64, 64), 256, 0, stream>>>(zn, rowsum);
    kfinal<<<N_ROWS / 4, 256, 0, stream>>>(zn, rowsum, out);
}

// Round 2
// 114.805 us; speedup vs baseline: 1.4669x; 1.4669x over previous
//
#include <hip/hip_runtime.h>
#include <hip/hip_bf16.h>

// NT-Xent loss, BS=4096, D=256, TAU=0.5.
// R2: exploit Gram symmetry (upper-triangular tiles only, row+col sums),
// extract sim_pos / diagonal from MFMA accumulators, no atomics, no memsets.
//
// knorm  : normalize fp32 -> bf16 zn[8192][256]
// kgemm  : 2080 triangular 128x128 tiles; P[strip][row] partial sums of
//          exp(sim/tau); selfdot/pairdot raw dots from tile diagonals
// kfinal : per-row loss, block partials (8)
// kreduce: scalar mean

#define N_ROWS 8192
#define BSZ    4096
#define DIM    256
#define INV_TAU 2.0f
#define EPS_REF 1e-8f
#define COS_EPS 1e-8f
#define NTILE   64                 // 8192 / 128

typedef __attribute__((ext_vector_type(8))) __bf16 bf16x8;
typedef __attribute__((ext_vector_type(4))) float  f32x4;

// ---------------- Kernel 1: row-normalize, emit bf16 zn[8192][256] ----------
__global__ __launch_bounds__(256) void knorm(const float* __restrict__ zi,
                                             const float* __restrict__ zj,
                                             __hip_bfloat16* __restrict__ zn) {
    const int row  = blockIdx.x * 4 + (threadIdx.x >> 6);
    const int lane = threadIdx.x & 63;
    const float* src = (row < BSZ) ? (zi + (size_t)row * DIM)
                                   : (zj + (size_t)(row - BSZ) * DIM);
    float4 v = ((const float4*)src)[lane];              // 4 elems/lane * 64 = 256
    float ss = v.x*v.x + v.y*v.y + v.z*v.z + v.w*v.w;
    #pragma unroll
    for (int off = 32; off >= 1; off >>= 1) ss += __shfl_xor(ss, off);
    const float inv = 1.0f / fmaxf(sqrtf(ss), COS_EPS);
    union { ushort4 u; __hip_bfloat16 h[4]; } o;
    o.h[0] = __float2bfloat16(v.x * inv);
    o.h[1] = __float2bfloat16(v.y * inv);
    o.h[2] = __float2bfloat16(v.z * inv);
    o.h[3] = __float2bfloat16(v.w * inv);
    ((ushort4*)zn)[(size_t)row * (DIM/4) + lane] = o.u;
}

// ---------------- Kernel 2: triangular Gram tiles ---------------------------
// P[s][r] = sum_{c in strip s} exp(sim[r][c]/tau), strips of 128 cols.
// Tile (bi,bj), bi<=bj: row sums -> P[bj][bi*128+..]; col sums -> P[bi][bj*128+..]
// (skip col sums if bi==bj; diag tile is symmetric).
// Diag raw dots: bi==bj -> selfdot; bj==bi+32 -> pairdot (rows i vs i+4096).
__global__ __launch_bounds__(256) void kgemm(const __hip_bfloat16* __restrict__ zn,
                                             float* __restrict__ P,
                                             float* __restrict__ selfdot,
                                             float* __restrict__ pairdot) {
    __shared__ __align__(16) __hip_bfloat16 As[128 * 64];
    __shared__ __align__(16) __hip_bfloat16 Bs[128 * 64];
    __shared__ float colpart[4][128];

    // decode upper-triangular tile index: start(bi) = bi*(129-bi)/2
    const int t = blockIdx.x;
    int bi = (int)((129.0f - sqrtf(16641.0f - 8.0f * (float)t)) * 0.5f);
    while ((bi + 1) * (129 - (bi + 1)) / 2 <= t) ++bi;   // fp safety fixup
    while (bi * (129 - bi) / 2 > t) --bi;
    const int bj = bi + (t - bi * (129 - bi) / 2);

    const int w = threadIdx.x >> 6;   // wave 0..3: rows w*32..w*32+31
    const int l = threadIdx.x & 63;

    f32x4 acc[2][8];
    #pragma unroll
    for (int mt = 0; mt < 2; ++mt)
        #pragma unroll
        for (int nt = 0; nt < 8; ++nt)
            acc[mt][nt] = (f32x4){0.f, 0.f, 0.f, 0.f};

    // staging geometry: 4 issues of 16B/lane per matrix per K-chunk.
    // LDS row stride 128B; 16B blocks XOR-swizzled by (row&7).
    int gA[4], gB[4], ldsOff[4];
    #pragma unroll
    for (int it = 0; it < 4; ++it) {
        const int off = it * 4096 + w * 1024 + l * 16;
        const int row = off >> 7;
        const int bst = (off >> 4) & 7;
        const int bg  = bst ^ (row & 7);
        gA[it] = (bi * 128 + row) * 512 + bg * 16;
        gB[it] = (bj * 128 + row) * 512 + bg * 16;
        ldsOff[it] = it * 4096 + w * 1024;
    }
    const char* gbase = (const char*)zn;

    #pragma unroll 1
    for (int kc = 0; kc < 4; ++kc) {
        __syncthreads();
        #pragma unroll
        for (int it = 0; it < 4; ++it) {
            __builtin_amdgcn_global_load_lds(
                (const __attribute__((address_space(1))) void*)(gbase + gA[it] + kc * 128),
                (__attribute__((address_space(3))) void*)((char*)As + ldsOff[it]),
                16, 0, 0);
            __builtin_amdgcn_global_load_lds(
                (const __attribute__((address_space(1))) void*)(gbase + gB[it] + kc * 128),
                (__attribute__((address_space(3))) void*)((char*)Bs + ldsOff[it]),
                16, 0, 0);
        }
        __syncthreads();
        #pragma unroll
        for (int ks = 0; ks < 2; ++ks) {
            bf16x8 af[2], bfr[8];
            #pragma unroll
            for (int mt = 0; mt < 2; ++mt) {
                const int r = w * 32 + mt * 16 + (l & 15);
                const int b = (ks * 4 + (l >> 4)) ^ (r & 7);
                af[mt] = *(const bf16x8*)((const char*)As + r * 128 + b * 16);
            }
            #pragma unroll
            for (int nt = 0; nt < 8; ++nt) {
                const int r = nt * 16 + (l & 15);
                const int b = (ks * 4 + (l >> 4)) ^ (r & 7);
                bfr[nt] = *(const bf16x8*)((const char*)Bs + r * 128 + b * 16);
            }
            #pragma unroll
            for (int mt = 0; mt < 2; ++mt)
                #pragma unroll
                for (int nt = 0; nt < 8; ++nt)
                    acc[mt][nt] = __builtin_amdgcn_mfma_f32_16x16x32_bf16(
                        af[mt], bfr[nt], acc[mt][nt], 0, 0, 0);
        }
    }

    // ---- epilogue ----
    // C/D layout (16x16x32): col = l&15, row = (l>>4)*4 + reg.
    const int c = l & 15, q = l >> 4;
    const int rsel = c - 4 * q;                 // valid reg if in [0,4)
    const bool valid = (rsel >= 0) && (rsel < 4);

    // raw diagonal values (before exp): sub-tile nt == w*2+mt holds the
    // tile-local diagonal for this wave's rows.
    float dv[2];
    #pragma unroll
    for (int mt = 0; mt < 2; ++mt) {
        f32x4 dsel = acc[mt][0];
        #pragma unroll
        for (int nt = 1; nt < 8; ++nt)
            if (w * 2 + mt == nt) dsel = acc[mt][nt];
        float d = dsel[0];
        #pragma unroll
        for (int r = 1; r < 4; ++r)
            if (rsel == r) d = dsel[r];
        dv[mt] = d;
    }

    // exp in place
    #pragma unroll
    for (int mt = 0; mt < 2; ++mt)
        #pragma unroll
        for (int nt = 0; nt < 8; ++nt)
            #pragma unroll
            for (int r = 0; r < 4; ++r)
                acc[mt][nt][r] = __expf(acc[mt][nt][r] * INV_TAU);

    // row sums: per lane over its 8 cols (one per nt), then xor over col bits.
    float rs[2][4] = {{0.f,0.f,0.f,0.f},{0.f,0.f,0.f,0.f}};
    #pragma unroll
    for (int mt = 0; mt < 2; ++mt)
        #pragma unroll
        for (int nt = 0; nt < 8; ++nt)
            #pragma unroll
            for (int r = 0; r < 4; ++r)
                rs[mt][r] += acc[mt][nt][r];
    #pragma unroll
    for (int off = 1; off <= 8; off <<= 1)
        #pragma unroll
        for (int mt = 0; mt < 2; ++mt)
            #pragma unroll
            for (int r = 0; r < 4; ++r)
                rs[mt][r] += __shfl_xor(rs[mt][r], off);
    if (c == 0) {
        #pragma unroll
        for (int mt = 0; mt < 2; ++mt)
            #pragma unroll
            for (int r = 0; r < 4; ++r)
                P[(size_t)bj * N_ROWS + bi * 128 + w * 32 + mt * 16 + q * 4 + r] = rs[mt][r];
    }

    // col sums: per lane over its 8 rows (mt x reg), xor over row-quad bits,
    // then combine the 4 waves via LDS.
    float cs[8];
    #pragma unroll
    for (int nt = 0; nt < 8; ++nt) {
        float s = 0.f;
        #pragma unroll
        for (int mt = 0; mt < 2; ++mt)
            #pragma unroll
            for (int r = 0; r < 4; ++r)
                s += acc[mt][nt][r];
        s += __shfl_xor(s, 16);
        s += __shfl_xor(s, 32);
        cs[nt] = s;
    }
    if (l < 16) {
        #pragma unroll
        for (int nt = 0; nt < 8; ++nt)
            colpart[w][nt * 16 + l] = cs[nt];
    }
    __syncthreads();
    if (bi != bj && threadIdx.x < 128) {
        const float s = colpart[0][threadIdx.x] + colpart[1][threadIdx.x]
                      + colpart[2][threadIdx.x] + colpart[3][threadIdx.x];
        P[(size_t)bi * N_ROWS + bj * 128 + threadIdx.x] = s;
    }

    // diagonal extracts
    if (valid) {
        #pragma unroll
        for (int mt = 0; mt < 2; ++mt) {
            const int idx = bi * 128 + w * 32 + mt * 16 + c;
            if (bi == bj)      selfdot[idx] = dv[mt];
            if (bj == bi + 32) pairdot[idx] = dv[mt];
        }
    }
}

// ---------------- Kernel 3: per-row loss, 8 block partials ------------------
__global__ __launch_bounds__(1024) void kfinal(const float* __restrict__ P,
                                               const float* __restrict__ selfdot,
                                               const float* __restrict__ pairdot,
                                               float* __restrict__ partial) {
    const int i = blockIdx.x * 1024 + threadIdx.x;
    float s = 0.f;
    #pragma unroll
    for (int st = 0; st < NTILE; ++st)
        s += P[(size_t)st * N_ROWS + i];
    const float selfe = __expf(selfdot[i] * INV_TAU);
    const float pd    = pairdot[(i < BSZ) ? i : i - BSZ];
    float loss = logf(s - selfe + EPS_REF) - pd * INV_TAU;
    #pragma unroll
    for (int off = 32; off >= 1; off >>= 1) loss += __shfl_xor(loss, off);
    __shared__ float wsum[16];
    if ((threadIdx.x & 63) == 0) wsum[threadIdx.x >> 6] = loss;
    __syncthreads();
    if (threadIdx.x == 0) {
        float tt = 0.f;
        #pragma unroll
        for (int k = 0; k < 16; ++k) tt += wsum[k];
        partial[blockIdx.x] = tt;
    }
}

__global__ void kreduce(const float* __restrict__ partial, float* __restrict__ out) {
    if (threadIdx.x == 0) {
        float s = 0.f;
        #pragma unroll
        for (int k = 0; k < 8; ++k) s += partial[k];
        out[0] = s * (1.0f / (float)N_ROWS);
    }
}

extern "C" void kernel_launch(void* const* d_in, const int* in_sizes, int n_in,
                              void* d_out, int out_size, void* d_ws, size_t ws_size,
                              hipStream_t stream) {
    const float* zi = (const float*)d_in[0];
    const float* zj = (const float*)d_in[1];
    float* out = (float*)d_out;

    char* ws = (char*)d_ws;
    __hip_bfloat16* zn = (__hip_bfloat16*)ws;                      // 4 MB
    float* P       = (float*)(ws + (size_t)N_ROWS * DIM * 2);      // 2 MB
    float* selfdot = (float*)(ws + 6 * 1024 * 1024);               // 32 KB
    float* pairdot = (float*)(ws + 6 * 1024 * 1024 + 32 * 1024);   // 16 KB
    float* partial = (float*)(ws + 6 * 1024 * 1024 + 48 * 1024);   // 32 B

    knorm  <<<N_ROWS / 4, 256, 0, stream>>>(zi, zj, zn);
    kgemm  <<<NTILE * (NTILE + 1) / 2, 256, 0, stream>>>(zn, P, selfdot, pairdot);
    kfinal <<<8, 1024, 0, stream>>>(P, selfdot, pairdot, partial);
    kreduce<<<1, 64, 0, stream>>>(partial, out);
}